// Round 1
// baseline (1008.592 us; speedup 1.0000x reference)
//
#include <hip/hip_runtime.h>
#include <cstdint>

#define S_LEN 2048
#define DMODEL 2560
#define NHEADS 32
#define HDIM 80
#define DINTER 10240

typedef unsigned short u16;
typedef __bf16 bf16x8 __attribute__((ext_vector_type(8)));
typedef float f32x4 __attribute__((ext_vector_type(4)));

__device__ __forceinline__ float us2f(u16 u) {
  return __builtin_bit_cast(float, ((uint32_t)u) << 16);
}
__device__ __forceinline__ u16 f2us(float f) {
  uint32_t x = __builtin_bit_cast(uint32_t, f);
  x += 0x7fffu + ((x >> 16) & 1u);
  return (u16)(x >> 16);
}

typedef __attribute__((address_space(1))) void gas_void;
typedef __attribute__((address_space(3))) void las_void;
__device__ __forceinline__ void gld16(const void* g, void* l) {
  __builtin_amdgcn_global_load_lds((gas_void*)g, (las_void*)l, 16, 0, 0);
}

#define VMW(N) asm volatile("s_waitcnt vmcnt(" #N ")" ::: "memory")
#define BARRIER()                          \
  do {                                     \
    asm volatile("" ::: "memory");         \
    __builtin_amdgcn_s_barrier();          \
    asm volatile("" ::: "memory");         \
  } while (0)

// ---------------------------------------------------------------------------
// fp32 -> bf16 conversion, 8 elements/thread
// ---------------------------------------------------------------------------
__global__ void f2b_kernel(const float* __restrict__ src, u16* __restrict__ dst) {
  const size_t i = ((size_t)blockIdx.x * 256 + threadIdx.x) * 8;
  const float4 a = *(const float4*)(src + i);
  const float4 b = *(const float4*)(src + i + 4);
  u16 o[8] = {f2us(a.x), f2us(a.y), f2us(a.z), f2us(a.w),
              f2us(b.x), f2us(b.y), f2us(b.z), f2us(b.w)};
  *(uint4*)(dst + i) = *(uint4*)o;
}

// ---------------------------------------------------------------------------
// out = x + wo_b[col] + w2_b[col]  (fp32)
// ---------------------------------------------------------------------------
__global__ void initout_kernel(const float* __restrict__ x,
                               const float* __restrict__ wo_b,
                               const float* __restrict__ w2_b,
                               float* __restrict__ out) {
  const size_t idx = ((size_t)blockIdx.x * 256 + threadIdx.x) * 4;
  const int c0 = (int)(idx % DMODEL);
  const float4 vx = *(const float4*)(x + idx);
  const float4 b1 = *(const float4*)(wo_b + c0);
  const float4 b2 = *(const float4*)(w2_b + c0);
  float4 vo;
  vo.x = vx.x + b1.x + b2.x;
  vo.y = vx.y + b1.y + b2.y;
  vo.z = vx.z + b1.z + b2.z;
  vo.w = vx.w + b1.w + b2.w;
  *(float4*)(out + idx) = vo;
}

// ---------------------------------------------------------------------------
// LayerNorm: fp32 in, bf16 out. One block per row (2560 = 256 x 10)
// ---------------------------------------------------------------------------
__global__ void ln_kernel(const float* __restrict__ x, const float* __restrict__ w,
                          const float* __restrict__ b, u16* __restrict__ h) {
  const int s = blockIdx.x, tid = threadIdx.x;
  const float* xr = x + (size_t)s * DMODEL;
  float v[10];
  float sum = 0.f, sq = 0.f;
#pragma unroll
  for (int j = 0; j < 10; j++) {
    v[j] = xr[tid + j * 256];
    sum += v[j];
    sq += v[j] * v[j];
  }
#pragma unroll
  for (int o = 32; o > 0; o >>= 1) {
    sum += __shfl_down(sum, o, 64);
    sq += __shfl_down(sq, o, 64);
  }
  __shared__ float red[8];
  const int wave = tid >> 6, lane = tid & 63;
  if (lane == 0) { red[wave] = sum; red[4 + wave] = sq; }
  __syncthreads();
  sum = red[0] + red[1] + red[2] + red[3];
  sq = red[4] + red[5] + red[6] + red[7];
  const float mu = sum * (1.0f / DMODEL);
  const float var = sq * (1.0f / DMODEL) - mu * mu;
  const float rstd = rsqrtf(var + 1e-5f);
  u16* hr = h + (size_t)s * DMODEL;
#pragma unroll
  for (int j = 0; j < 10; j++) {
    const int d = tid + j * 256;
    hr[d] = f2us((v[j] - mu) * rstd * w[d] + b[d]);
  }
}

// ---------------------------------------------------------------------------
// 256x256 8-phase GEMM: C[M][N] = act(A[M][K] * B[N][K]^T [+ bias[N]]).
// 512 thr = 8 waves (2M x 4N); per-wave 128x64 out as 2x2 quadrants of
// (4mf x 2nf) 16x16 frags; BK=64 (2 MFMA K-steps).  LDS 128 KiB:
// [buf0A, buf0B, buf1A, buf1B] x 32 KiB, double-buffered.
//
// Schedule per K-tile (4 phases), 2 tiles per "8-phase" iteration:
//   P1: ds_read A-half0 + B-half0 | stage B0(t+1) | vmcnt(6) bar | MFMA(0,0) bar
//   P2: ds_read B-half1           | stage B1(t+1) | vmcnt(6) bar | MFMA(0,1) bar
//   P3: ds_read A-half1           | stage A1(t+1) |          bar | MFMA(1,1) bar
//   P4:  (regs held)              | stage A0(t+2) | vmcnt(6) bar | MFMA(1,0) bar
// Counted vmcnt retires exactly the half-tile the next reader needs; loads
// stay in flight across barriers (never vmcnt(0) in the main loop).  Buffer t
// is last ds_read at P3, so P4 may overwrite it with tile t+2's A0.
// Tail: peel nk-2 (vmcnt 6,6,-,4) and nk-1 (vmcnt 2,0).
//
// LDS st-swizzle: byte ^= ((byte>>9)&1)<<5, realized as pre-swizzled GLOBAL
// source (global_load_lds dest must stay linear) + swizzled ds_read address.
// Gives uniform 8-lanes-per-16B-slot distribution on every ds_read_b128.
// ---------------------------------------------------------------------------
template <int ACT, int MODE>
__launch_bounds__(512, 2)
__global__ void gemm256(const u16* __restrict__ A, const u16* __restrict__ B,
                        const float* __restrict__ bias, void* __restrict__ Cv,
                        int M, int N, int K) {
  __shared__ __align__(16) u16 lds[4][16384];  // 128 KiB
  const int tid = threadIdx.x;
  const int w = tid >> 6, lane = tid & 63;
  const int quad = lane >> 4, l15 = lane & 15;
  const int wm = w >> 2, wn = w & 3;

  // XCD-aware bijective swizzle (nwg % 8 == 0 for all call sites);
  // consecutive swz within an XCD share bm -> A-panel L2-resident.
  const int nwg = gridDim.x * gridDim.y;
  const int flat = blockIdx.x + gridDim.x * blockIdx.y;
  const int swz = (flat & 7) * (nwg >> 3) + (flat >> 3);
  const int ntN = N >> 8;
  const int bm = swz / ntN, bn = swz % ntN;

  const int Kc = K / gridDim.z;
  const int k0 = blockIdx.z * Kc;
  const int nk = Kc >> 6;  // #K-tiles (>=2 at every call site)

  // staging: lane covers row (w*8 + lane>>3) of a 64-row quarter; source
  // column pre-swizzled so linear LDS write == st-swizzled layout
  const int stgCol = ((lane & 7) * 8) ^ (((lane >> 5) & 1) * 16);
  const u16* Ag = A + ((size_t)bm * 256 + w * 8 + (lane >> 3)) * K + k0 + stgCol;
  const u16* Bg = B + ((size_t)bn * 256 + w * 8 + (lane >> 3)) * K + k0 + stgCol;

  // ds_read swizzle term (row bit2 == l15 bit2 since all bases are x16)
  const int qa = (quad * 8) ^ (((l15 >> 2) & 1) * 16);
  const int arow = wm * 64 + l15;
  const int brow = wn * 32 + l15;

#define STG_HALF(MAT, GP, BUF, HF, KT)                                       \
  do {                                                                       \
    gld16((GP) + (size_t)((HF) * 128) * K + (KT) * 64,                       \
          &lds[(BUF) * 2 + (MAT)][(HF) * 8192 + w * 512]);                   \
    gld16((GP) + (size_t)((HF) * 128 + 64) * K + (KT) * 64,                  \
          &lds[(BUF) * 2 + (MAT)][(HF) * 8192 + 4096 + w * 512]);            \
  } while (0)

#define LD_A(BUF, MH)                                                        \
  _Pragma("unroll") for (int mf_ = 0; mf_ < 4; mf_++)                        \
  _Pragma("unroll") for (int kk_ = 0; kk_ < 2; kk_++)                        \
      aF[mf_][kk_] = *(const bf16x8*)&lds[(BUF) * 2]                         \
          [(arow + (MH) * 128 + mf_ * 16) * 64 + kk_ * 32 + qa];

#define LD_B(DST, BUF, NH)                                                   \
  _Pragma("unroll") for (int nf_ = 0; nf_ < 2; nf_++)                        \
  _Pragma("unroll") for (int kk_ = 0; kk_ < 2; kk_++)                        \
      DST[nf_][kk_] = *(const bf16x8*)&lds[(BUF) * 2 + 1]                    \
          [(brow + (NH) * 128 + nf_ * 16) * 64 + kk_ * 32 + qa];

#define MFMA_Q(MH, NH, BF)                                                   \
  do {                                                                       \
    __builtin_amdgcn_s_setprio(1);                                           \
    _Pragma("unroll") for (int kk_ = 0; kk_ < 2; kk_++)                      \
    _Pragma("unroll") for (int mf_ = 0; mf_ < 4; mf_++)                      \
    _Pragma("unroll") for (int nf_ = 0; nf_ < 2; nf_++)                      \
        acc[(MH) * 4 + mf_][(NH) * 2 + nf_] =                                \
            __builtin_amdgcn_mfma_f32_16x16x32_bf16(                         \
                aF[mf_][kk_], BF[nf_][kk_],                                  \
                acc[(MH) * 4 + mf_][(NH) * 2 + nf_], 0, 0, 0);               \
    __builtin_amdgcn_s_setprio(0);                                           \
  } while (0)

  f32x4 acc[8][4] = {};
  bf16x8 aF[4][2], bF0[2][2], bF1[2][2];

  // prologue: tile0 A0,B0,B1,A1 -> buf0 (deadline order!), A0(tile1) -> buf1
  STG_HALF(0, Ag, 0, 0, 0);
  STG_HALF(1, Bg, 0, 0, 0);
  STG_HALF(1, Bg, 0, 1, 0);
  STG_HALF(0, Ag, 0, 1, 0);
  STG_HALF(0, Ag, 1, 0, 1);
  VMW(6);  // A0(t0), B0(t0) resident
  BARRIER();

  for (int t = 0; t < nk - 2; ++t) {
    const int bc = t & 1, ob = bc ^ 1;
    // P1
    LD_A(bc, 0);
    LD_B(bF0, bc, 0);
    STG_HALF(1, Bg, ob, 0, t + 1);
    VMW(6);  // retires B1(t)
    BARRIER();
    MFMA_Q(0, 0, bF0);
    BARRIER();
    // P2
    LD_B(bF1, bc, 1);
    STG_HALF(1, Bg, ob, 1, t + 1);
    VMW(6);  // retires A1(t)
    BARRIER();
    MFMA_Q(0, 1, bF1);
    BARRIER();
    // P3
    LD_A(bc, 1);
    STG_HALF(0, Ag, ob, 1, t + 1);
    BARRIER();
    MFMA_Q(1, 1, bF1);
    BARRIER();
    // P4 (buffer bc fully read at P3 -> safe to stage tile t+2 into it)
    STG_HALF(0, Ag, bc, 0, t + 2);
    VMW(6);  // retires A0(t+1), B0(t+1)
    BARRIER();
    MFMA_Q(1, 0, bF0);
    BARRIER();
  }
  {  // tile nk-2: stage only the remaining halves of tile nk-1
    const int bc = (nk - 2) & 1, ob = bc ^ 1;
    LD_A(bc, 0);
    LD_B(bF0, bc, 0);
    STG_HALF(1, Bg, ob, 0, nk - 1);
    VMW(6);
    BARRIER();
    MFMA_Q(0, 0, bF0);
    BARRIER();
    LD_B(bF1, bc, 1);
    STG_HALF(1, Bg, ob, 1, nk - 1);
    VMW(6);
    BARRIER();
    MFMA_Q(0, 1, bF1);
    BARRIER();
    LD_A(bc, 1);
    STG_HALF(0, Ag, ob, 1, nk - 1);
    BARRIER();
    MFMA_Q(1, 1, bF1);
    BARRIER();
    VMW(4);  // retires A0(nk-1), B0(nk-1)
    BARRIER();
    MFMA_Q(1, 0, bF0);
    BARRIER();
  }
  {  // tile nk-1: drain 2 -> 0
    const int bc = (nk - 1) & 1;
    LD_A(bc, 0);
    LD_B(bF0, bc, 0);
    VMW(2);
    BARRIER();
    MFMA_Q(0, 0, bF0);
    BARRIER();
    LD_B(bF1, bc, 1);
    VMW(0);
    BARRIER();
    MFMA_Q(0, 1, bF1);
    BARRIER();
    LD_A(bc, 1);
    BARRIER();
    MFMA_Q(1, 1, bF1);
    MFMA_Q(1, 0, bF0);
  }

#pragma unroll
  for (int nh = 0; nh < 2; nh++)
#pragma unroll
    for (int nf = 0; nf < 2; nf++) {
      const int col = bn * 256 + nh * 128 + wn * 32 + nf * 16 + l15;
      const float bv = (MODE == 0) ? bias[col] : 0.f;
#pragma unroll
      for (int mh = 0; mh < 2; mh++)
#pragma unroll
        for (int mf = 0; mf < 4; mf++) {
          const int row0 = bm * 256 + mh * 128 + wm * 64 + mf * 16 + quad * 4;
#pragma unroll
          for (int r = 0; r < 4; r++) {
            float v = acc[mh * 4 + mf][nh * 2 + nf][r] + bv;
            if (ACT == 1) {
              const float tt = v * (0.7978845608f + 0.0356774081f * v * v);
              v = 0.5f * v * (1.0f + tanhf(tt));
            }
            if (MODE == 0)
              ((u16*)Cv)[(size_t)(row0 + r) * N + col] = f2us(v);
            else
              atomicAdd((float*)Cv + (size_t)(row0 + r) * N + col, v);
          }
        }
    }
#undef STG_HALF
#undef LD_A
#undef LD_B
#undef MFMA_Q
}

// ---------------------------------------------------------------------------
// RoPE in-place on bf16 qkv (q and k sections, first 32 dims of each head).
// ---------------------------------------------------------------------------
__global__ void rope_kernel(u16* __restrict__ qkv, const int* __restrict__ pos) {
  const int idx = blockIdx.x * 256 + threadIdx.x;
  const int i = idx & 15;
  const int which = (idx >> 4) & 1;
  const int hh = (idx >> 5) & 31;
  const int s = idx >> 10;
  const float p = (float)pos[s];
  const float freq = p * expf(-0.57564627324851f * (float)i);
  float sn, c;
  sincosf(freq, &sn, &c);
  u16* base = qkv + (size_t)s * (3 * DMODEL) + which * DMODEL + hh * HDIM + i;
  const float t0 = us2f(base[0]), t1 = us2f(base[16]);
  base[0] = f2us(t0 * c - t1 * sn);
  base[16] = f2us(t1 * c + t0 * sn);
}

// ---------------------------------------------------------------------------
// Flash attention (causal), bf16. Grid (S/64, H), 256 thr = 4 waves; each
// wave owns 16 q-rows. KT=64 keys/iter. hd 80 padded to 96 for 3 K=32 MFMA
// steps. Conflict-free strides: Qs/Ks 104, Vts 88, Ps two 16x40 tiles.
// ---------------------------------------------------------------------------
__global__ void attn_kernel(const u16* __restrict__ qkv, u16* __restrict__ y) {
  const int qt = (int)gridDim.x - 1 - (int)blockIdx.x;  // longest first
  const int h = blockIdx.y;
  const int tid = threadIdx.x, wave = tid >> 6, lane = tid & 63;
  const int quad = lane >> 4, l15 = lane & 15;
  const int qbase = qt * 64;

  __shared__ __align__(16) u16 Qs[64 * 104];
  __shared__ __align__(16) u16 Ks[64 * 104];
  __shared__ __align__(16) u16 Vts[80 * 88];   // [dim][key], stride 88
  __shared__ __align__(16) u16 Ps[4][2][16 * 40];

  for (int i = tid; i < 64 * 104; i += 256) { Qs[i] = 0; Ks[i] = 0; }
  __syncthreads();

  {  // stage Q once, folding in 1/sqrt(80)
    const int r = tid >> 2, c = tid & 3;
    const u16* src = qkv + (size_t)(qbase + r) * (3 * DMODEL) + h * HDIM + c * 20;
    u16* dst = Qs + r * 104 + c * 20;
#pragma unroll
    for (int j = 0; j < 5; j++) {
      ushort4 uv = *(const ushort4*)(src + j * 4);
      ushort4 ov;
      ov.x = f2us(us2f(uv.x) * 0.11180339887f);
      ov.y = f2us(us2f(uv.y) * 0.11180339887f);
      ov.z = f2us(us2f(uv.z) * 0.11180339887f);
      ov.w = f2us(us2f(uv.w) * 0.11180339887f);
      *(ushort4*)(dst + j * 4) = ov;
    }
  }

  float m_i[4], l_i[4];
  f32x4 oacc[5] = {};
#pragma unroll
  for (int r = 0; r < 4; r++) { m_i[r] = -1e30f; l_i[r] = 0.f; }

  const int n_iter = qt + 1;
  __syncthreads();

  for (int it = 0; it < n_iter; ++it) {
    const int kc0 = it * 64;
    if (tid < 128) {  // waves 0-1: stage 64 K rows (2 threads/row)
      const int r = tid >> 1, c = (tid & 1) * 40;
      const u16* src =
          qkv + (size_t)(kc0 + r) * (3 * DMODEL) + DMODEL + h * HDIM + c;
      u16* dst = Ks + r * 104 + c;
#pragma unroll
      for (int j = 0; j < 10; j++)
        *(ushort4*)(dst + j * 4) = *(const ushort4*)(src + j * 4);
    } else {  // waves 2-3: stage 64 V rows transposed
      const int u = tid - 128;
      const int r = u >> 1, c0 = (u & 1) * 40;
      const u16* src =
          qkv + (size_t)(kc0 + r) * (3 * DMODEL) + 2 * DMODEL + h * HDIM + c0;
#pragma unroll
      for (int j = 0; j < 10; j++) {
        ushort4 vv = *(const ushort4*)(src + j * 4);
        const int d0 = c0 + j * 4;
        Vts[(d0 + 0) * 88 + r] = vv.x;
        Vts[(d0 + 1) * 88 + r] = vv.y;
        Vts[(d0 + 2) * 88 + r] = vv.z;
        Vts[(d0 + 3) * 88 + r] = vv.w;
      }
    }
    __syncthreads();

    // S = Q K^T : 16 rows x 64 cols per wave, 3 K-steps over padded hd=96
    f32x4 st[4] = {};
    bf16x8 aq[3];
#pragma unroll
    for (int ks = 0; ks < 3; ks++)
      aq[ks] = *(const bf16x8*)&Qs[(wave * 16 + l15) * 104 + ks * 32 + quad * 8];
#pragma unroll
    for (int ks = 0; ks < 3; ks++)
#pragma unroll
      for (int t = 0; t < 4; t++) {
        bf16x8 bk = *(const bf16x8*)&Ks[(t * 16 + l15) * 104 + ks * 32 + quad * 8];
        st[t] = __builtin_amdgcn_mfma_f32_16x16x32_bf16(aq[ks], bk, st[t], 0, 0, 0);
      }

    // causal mask + online softmax (rows = quad*4+r, cols = t*16+l15)
    float sv[4][4], mx[4];
#pragma unroll
    for (int r = 0; r < 4; r++) {
      const int qr = qbase + wave * 16 + quad * 4 + r;
#pragma unroll
      for (int t = 0; t < 4; t++) {
        const int kc = kc0 + t * 16 + l15;
        sv[t][r] = (kc <= qr) ? st[t][r] : -1e30f;
      }
      mx[r] = fmaxf(fmaxf(sv[0][r], sv[1][r]), fmaxf(sv[2][r], sv[3][r]));
    }
#pragma unroll
    for (int o = 1; o < 16; o <<= 1)
#pragma unroll
      for (int r = 0; r < 4; r++) mx[r] = fmaxf(mx[r], __shfl_xor(mx[r], o, 64));

    float alpha[4], rs[4];
#pragma unroll
    for (int r = 0; r < 4; r++) {
      const float mnew = fmaxf(m_i[r], mx[r]);
      alpha[r] = __expf(m_i[r] - mnew);
      m_i[r] = mnew;
      const float p0 = __expf(sv[0][r] - mnew);
      const float p1 = __expf(sv[1][r] - mnew);
      const float p2 = __expf(sv[2][r] - mnew);
      const float p3 = __expf(sv[3][r] - mnew);
      rs[r] = (p0 + p1) + (p2 + p3);
      const int ro = (quad * 4 + r) * 40;
      Ps[wave][0][ro + l15] = f2us(p0);
      Ps[wave][0][ro + 16 + l15] = f2us(p1);
      Ps[wave][1][ro + l15] = f2us(p2);
      Ps[wave][1][ro + 16 + l15] = f2us(p3);
    }
#pragma unroll
    for (int o = 1; o < 16; o <<= 1)
#pragma unroll
      for (int r = 0; r < 4; r++) rs[r] += __shfl_xor(rs[r], o, 64);
#pragma unroll
    for (int r = 0; r < 4; r++) l_i[r] = l_i[r] * alpha[r] + rs[r];
#pragma unroll
    for (int dt = 0; dt < 5; dt++)
#pragma unroll
      for (int r = 0; r < 4; r++) oacc[dt][r] *= alpha[r];

    // O += P V  (P via per-wave LDS round-trip into A-layout)
    bf16x8 pf0 = *(const bf16x8*)&Ps[wave][0][l15 * 40 + quad * 8];
    bf16x8 pf1 = *(const bf16x8*)&Ps[wave][1][l15 * 40 + quad * 8];
#pragma unroll
    for (int dt = 0; dt < 5; dt++) {
      bf16x8 vf0 = *(const bf16x8*)&Vts[(dt * 16 + l15) * 88 + quad * 8];
      bf16x8 vf1 = *(const bf16x8*)&Vts[(dt * 16 + l15) * 88 + 32 + quad * 8];
      oacc[dt] = __builtin_amdgcn_mfma_f32_16x16x32_bf16(pf0, vf0, oacc[dt], 0, 0, 0);
      oacc[dt] = __builtin_amdgcn_mfma_f32_16x16x32_bf16(pf1, vf1, oacc[dt], 0, 0, 0);
    }
    __syncthreads();
  }

#pragma unroll
  for (int dt = 0; dt < 5; dt++)
#pragma unroll
    for (int r = 0; r < 4; r++) {
      const int row = qbase + wave * 16 + quad * 4 + r;
      y[(size_t)row * DMODEL + h * HDIM + dt * 16 + l15] = f2us(oacc[dt][r] / l_i[r]);
    }
}

extern "C" void kernel_launch(void* const* d_in, const int* in_sizes, int n_in,
                              void* d_out, int out_size, void* d_ws, size_t ws_size,
                              hipStream_t stream) {
  const float* x = (const float*)d_in[0];
  const int* pos = (const int*)d_in[1];
  const float* ln_w = (const float*)d_in[3];
  const float* ln_b = (const float*)d_in[4];
  const float* wqkv_w = (const float*)d_in[5];
  const float* wqkv_b = (const float*)d_in[6];
  const float* wo_w = (const float*)d_in[7];
  const float* wo_b = (const float*)d_in[8];
  const float* w1_w = (const float*)d_in[9];
  const float* w1_b = (const float*)d_in[10];
  const float* w2_w = (const float*)d_in[11];
  const float* w2_b = (const float*)d_in[12];
  float* out = (float*)d_out;

  char* ws = (char*)d_ws;
  // layout (100 MB):
  //   [0,        52428800)  wbuf (bf16 weights, reused 4x)
  //   [52428800, 62914560)  h bf16
  //   [62914560, 104857600) ffn1 bf16 (42MB) -> later qkv (31.5) + yAtt (10.5)
  u16* wbuf = (u16*)(ws);
  u16* h = (u16*)(ws + 52428800);
  u16* ffn1 = (u16*)(ws + 62914560);
  u16* qkv = (u16*)(ws + 62914560);
  u16* yAtt = (u16*)(ws + 94371840);

  ln_kernel<<<S_LEN, 256, 0, stream>>>(x, ln_w, ln_b, h);
  initout_kernel<<<(S_LEN * DMODEL / 4) / 256, 256, 0, stream>>>(x, wo_b, w2_b, out);

  // FFN branch (ffn1 dies before qkv overlays it)
  f2b_kernel<<<(DINTER * DMODEL) / 2048, 256, 0, stream>>>(w1_w, wbuf);
  gemm256<1, 0><<<dim3(DINTER / 256, S_LEN / 256, 1), 512, 0, stream>>>(
      h, wbuf, w1_b, ffn1, S_LEN, DINTER, DMODEL);
  f2b_kernel<<<(DMODEL * DINTER) / 2048, 256, 0, stream>>>(w2_w, wbuf);
  gemm256<0, 2><<<dim3(DMODEL / 256, S_LEN / 256, 5), 512, 0, stream>>>(
      ffn1, wbuf, w2_b, out, S_LEN, DMODEL, DINTER);

  // Attention branch
  f2b_kernel<<<(3 * DMODEL * DMODEL) / 2048, 256, 0, stream>>>(wqkv_w, wbuf);
  gemm256<0, 0><<<dim3(3 * DMODEL / 256, S_LEN / 256, 1), 512, 0, stream>>>(
      h, wbuf, wqkv_b, qkv, S_LEN, 3 * DMODEL, DMODEL);
  rope_kernel<<<(S_LEN * NHEADS * 2 * 16) / 256, 256, 0, stream>>>(qkv, pos);
  attn_kernel<<<dim3(S_LEN / 64, NHEADS), 256, 0, stream>>>(qkv, yAtt);
  f2b_kernel<<<(DMODEL * DMODEL) / 2048, 256, 0, stream>>>(wo_w, wbuf);
  gemm256<0, 2><<<dim3(DMODEL / 256, S_LEN / 256, 2), 512, 0, stream>>>(
      yAtt, wbuf, wo_b, out, S_LEN, DMODEL, DMODEL);
}

// Round 2
// 973.673 us; speedup vs baseline: 1.0359x; 1.0359x over previous
//
#include <hip/hip_runtime.h>
#include <cstdint>

#define S_LEN 2048
#define DMODEL 2560
#define NHEADS 32
#define HDIM 80
#define DINTER 10240

typedef unsigned short u16;
typedef __bf16 bf16x8 __attribute__((ext_vector_type(8)));
typedef float f32x4 __attribute__((ext_vector_type(4)));

__device__ __forceinline__ float us2f(u16 u) {
  return __builtin_bit_cast(float, ((uint32_t)u) << 16);
}
__device__ __forceinline__ u16 f2us(float f) {
  uint32_t x = __builtin_bit_cast(uint32_t, f);
  x += 0x7fffu + ((x >> 16) & 1u);
  return (u16)(x >> 16);
}

typedef __attribute__((address_space(1))) void gas_void;
typedef __attribute__((address_space(3))) void las_void;
__device__ __forceinline__ void gld16(const void* g, void* l) {
  __builtin_amdgcn_global_load_lds((gas_void*)g, (las_void*)l, 16, 0, 0);
}

#define VMW(N) asm volatile("s_waitcnt vmcnt(" #N ")" ::: "memory")
#define BARRIER()                          \
  do {                                     \
    asm volatile("" ::: "memory");         \
    __builtin_amdgcn_s_barrier();          \
    asm volatile("" ::: "memory");         \
  } while (0)

// ---------------------------------------------------------------------------
// fp32 -> bf16 conversion, 8 elements/thread
// ---------------------------------------------------------------------------
__global__ void f2b_kernel(const float* __restrict__ src, u16* __restrict__ dst) {
  const size_t i = ((size_t)blockIdx.x * 256 + threadIdx.x) * 8;
  const float4 a = *(const float4*)(src + i);
  const float4 b = *(const float4*)(src + i + 4);
  u16 o[8] = {f2us(a.x), f2us(a.y), f2us(a.z), f2us(a.w),
              f2us(b.x), f2us(b.y), f2us(b.z), f2us(b.w)};
  *(uint4*)(dst + i) = *(uint4*)o;
}

// ---------------------------------------------------------------------------
// out = x + wo_b[col] + w2_b[col]  (fp32)
// ---------------------------------------------------------------------------
__global__ void initout_kernel(const float* __restrict__ x,
                               const float* __restrict__ wo_b,
                               const float* __restrict__ w2_b,
                               float* __restrict__ out) {
  const size_t idx = ((size_t)blockIdx.x * 256 + threadIdx.x) * 4;
  const int c0 = (int)(idx % DMODEL);
  const float4 vx = *(const float4*)(x + idx);
  const float4 b1 = *(const float4*)(wo_b + c0);
  const float4 b2 = *(const float4*)(w2_b + c0);
  float4 vo;
  vo.x = vx.x + b1.x + b2.x;
  vo.y = vx.y + b1.y + b2.y;
  vo.z = vx.z + b1.z + b2.z;
  vo.w = vx.w + b1.w + b2.w;
  *(float4*)(out + idx) = vo;
}

// ---------------------------------------------------------------------------
// LayerNorm: fp32 in, bf16 out. One block per row (2560 = 256 x 10)
// ---------------------------------------------------------------------------
__global__ void ln_kernel(const float* __restrict__ x, const float* __restrict__ w,
                          const float* __restrict__ b, u16* __restrict__ h) {
  const int s = blockIdx.x, tid = threadIdx.x;
  const float* xr = x + (size_t)s * DMODEL;
  float v[10];
  float sum = 0.f, sq = 0.f;
#pragma unroll
  for (int j = 0; j < 10; j++) {
    v[j] = xr[tid + j * 256];
    sum += v[j];
    sq += v[j] * v[j];
  }
#pragma unroll
  for (int o = 32; o > 0; o >>= 1) {
    sum += __shfl_down(sum, o, 64);
    sq += __shfl_down(sq, o, 64);
  }
  __shared__ float red[8];
  const int wave = tid >> 6, lane = tid & 63;
  if (lane == 0) { red[wave] = sum; red[4 + wave] = sq; }
  __syncthreads();
  sum = red[0] + red[1] + red[2] + red[3];
  sq = red[4] + red[5] + red[6] + red[7];
  const float mu = sum * (1.0f / DMODEL);
  const float var = sq * (1.0f / DMODEL) - mu * mu;
  const float rstd = rsqrtf(var + 1e-5f);
  u16* hr = h + (size_t)s * DMODEL;
#pragma unroll
  for (int j = 0; j < 10; j++) {
    const int d = tid + j * 256;
    hr[d] = f2us((v[j] - mu) * rstd * w[d] + b[d]);
  }
}

// ---------------------------------------------------------------------------
// 256x256 8-phase GEMM: C[M][N] = act(A[M][K] * B[N][K]^T [+ bias[N]]).
// 512 thr = 8 waves (2M x 4N); per-wave 128x64 out as 2x2 quadrants of
// (4mf x 2nf) 16x16 frags; BK=64 (2 MFMA K-steps).  LDS 128 KiB:
// [buf0A, buf0B, buf1A, buf1B] x 32 KiB, double-buffered.
//
// Schedule per K-tile (4 phases), 2 tiles per "8-phase" iteration:
//   P1: ds_read A-half0 + B-half0 | stage B0(t+1) | vmcnt(6) bar | MFMA(0,0) bar
//   P2: ds_read B-half1           | stage B1(t+1) | vmcnt(6) bar | MFMA(0,1) bar
//   P3: ds_read A-half1           | stage A1(t+1) |          bar | MFMA(1,1) bar
//   P4:  (regs held)              | stage A0(t+2) | vmcnt(6) bar | MFMA(1,0) bar
// Counted vmcnt retires exactly the half-tile the next reader needs; loads
// stay in flight across barriers (never vmcnt(0) in the main loop).  Buffer t
// is last ds_read at P3, so P4 may overwrite it with tile t+2's A0.
// Tail: peel nk-2 (vmcnt 6,6,-,4) and nk-1 (vmcnt 2,0).
//
// LDS swizzle (full 3-bit, G4 formula): physical_byte = logical_byte ^
// ((row&7)<<4).  A wave64 ds_read_b128 then lands 8 lanes on each of the 8
// 16B slots of a 128B bank-row (slot' = (kk*4+quad)^(l15&7)) -> zero
// conflicts.  Realized as pre-swizzled GLOBAL source (global_load_lds dest
// must stay linear; lane's logical slot = (lane&7)^((lane>>3)&7)) +
// swizzled ds_read col ((kk*32+quad*8)^((l15&7)*8); every fragment row base
// is a multiple of 8 so row&7 == l15&7).
// ---------------------------------------------------------------------------
template <int ACT, int MODE>
__launch_bounds__(512, 2)
__global__ void gemm256(const u16* __restrict__ A, const u16* __restrict__ B,
                        const float* __restrict__ bias, void* __restrict__ Cv,
                        int M, int N, int K) {
  __shared__ __align__(16) u16 lds[4][16384];  // 128 KiB
  const int tid = threadIdx.x;
  const int w = tid >> 6, lane = tid & 63;
  const int quad = lane >> 4, l15 = lane & 15;
  const int wm = w >> 2, wn = w & 3;

  // XCD-aware bijective swizzle (nwg % 8 == 0 for all call sites);
  // consecutive swz within an XCD share bm -> A-panel L2-resident.
  const int nwg = gridDim.x * gridDim.y;
  const int flat = blockIdx.x + gridDim.x * blockIdx.y;
  const int swz = (flat & 7) * (nwg >> 3) + (flat >> 3);
  const int ntN = N >> 8;
  const int bm = swz / ntN, bn = swz % ntN;

  const int Kc = K / gridDim.z;
  const int k0 = blockIdx.z * Kc;
  const int nk = Kc >> 6;  // #K-tiles (>=2 at every call site)

  // staging: lane covers row (w*8 + lane>>3) of a 64-row quarter; source
  // column pre-swizzled so linear LDS write == swizzled layout
  const int stgCol = (((lane & 7) ^ ((lane >> 3) & 7)) * 8);
  const u16* Ag = A + ((size_t)bm * 256 + w * 8 + (lane >> 3)) * K + k0 + stgCol;
  const u16* Bg = B + ((size_t)bn * 256 + w * 8 + (lane >> 3)) * K + k0 + stgCol;

  // ds_read swizzle terms (row&7 == l15&7 for every fragment row)
  const int q8 = quad * 8;
  const int swz3 = (l15 & 7) * 8;
  const int arow = wm * 64 + l15;
  const int brow = wn * 32 + l15;

#define STG_HALF(MAT, GP, BUF, HF, KT)                                       \
  do {                                                                       \
    gld16((GP) + (size_t)((HF) * 128) * K + (KT) * 64,                       \
          &lds[(BUF) * 2 + (MAT)][(HF) * 8192 + w * 512]);                   \
    gld16((GP) + (size_t)((HF) * 128 + 64) * K + (KT) * 64,                  \
          &lds[(BUF) * 2 + (MAT)][(HF) * 8192 + 4096 + w * 512]);            \
  } while (0)

#define LD_A(BUF, MH)                                                        \
  _Pragma("unroll") for (int mf_ = 0; mf_ < 4; mf_++)                        \
  _Pragma("unroll") for (int kk_ = 0; kk_ < 2; kk_++)                        \
      aF[mf_][kk_] = *(const bf16x8*)&lds[(BUF) * 2]                         \
          [(arow + (MH) * 128 + mf_ * 16) * 64 + ((kk_ * 32 + q8) ^ swz3)];

#define LD_B(DST, BUF, NH)                                                   \
  _Pragma("unroll") for (int nf_ = 0; nf_ < 2; nf_++)                        \
  _Pragma("unroll") for (int kk_ = 0; kk_ < 2; kk_++)                        \
      DST[nf_][kk_] = *(const bf16x8*)&lds[(BUF) * 2 + 1]                    \
          [(brow + (NH) * 128 + nf_ * 16) * 64 + ((kk_ * 32 + q8) ^ swz3)];

#define MFMA_Q(MH, NH, BF)                                                   \
  do {                                                                       \
    __builtin_amdgcn_s_setprio(1);                                           \
    _Pragma("unroll") for (int kk_ = 0; kk_ < 2; kk_++)                      \
    _Pragma("unroll") for (int mf_ = 0; mf_ < 4; mf_++)                      \
    _Pragma("unroll") for (int nf_ = 0; nf_ < 2; nf_++)                      \
        acc[(MH) * 4 + mf_][(NH) * 2 + nf_] =                                \
            __builtin_amdgcn_mfma_f32_16x16x32_bf16(                         \
                aF[mf_][kk_], BF[nf_][kk_],                                  \
                acc[(MH) * 4 + mf_][(NH) * 2 + nf_], 0, 0, 0);               \
    __builtin_amdgcn_s_setprio(0);                                           \
  } while (0)

  f32x4 acc[8][4] = {};
  bf16x8 aF[4][2], bF0[2][2], bF1[2][2];

  // prologue: tile0 A0,B0,B1,A1 -> buf0 (deadline order!), A0(tile1) -> buf1
  STG_HALF(0, Ag, 0, 0, 0);
  STG_HALF(1, Bg, 0, 0, 0);
  STG_HALF(1, Bg, 0, 1, 0);
  STG_HALF(0, Ag, 0, 1, 0);
  STG_HALF(0, Ag, 1, 0, 1);
  VMW(6);  // A0(t0), B0(t0) resident
  BARRIER();

  for (int t = 0; t < nk - 2; ++t) {
    const int bc = t & 1, ob = bc ^ 1;
    // P1
    LD_A(bc, 0);
    LD_B(bF0, bc, 0);
    STG_HALF(1, Bg, ob, 0, t + 1);
    VMW(6);  // retires B1(t)
    BARRIER();
    MFMA_Q(0, 0, bF0);
    BARRIER();
    // P2
    LD_B(bF1, bc, 1);
    STG_HALF(1, Bg, ob, 1, t + 1);
    VMW(6);  // retires A1(t)
    BARRIER();
    MFMA_Q(0, 1, bF1);
    BARRIER();
    // P3
    LD_A(bc, 1);
    STG_HALF(0, Ag, ob, 1, t + 1);
    BARRIER();
    MFMA_Q(1, 1, bF1);
    BARRIER();
    // P4 (buffer bc fully read at P3 -> safe to stage tile t+2 into it)
    STG_HALF(0, Ag, bc, 0, t + 2);
    VMW(6);  // retires A0(t+1), B0(t+1)
    BARRIER();
    MFMA_Q(1, 0, bF0);
    BARRIER();
  }
  {  // tile nk-2: stage only the remaining halves of tile nk-1
    const int bc = (nk - 2) & 1, ob = bc ^ 1;
    LD_A(bc, 0);
    LD_B(bF0, bc, 0);
    STG_HALF(1, Bg, ob, 0, nk - 1);
    VMW(6);
    BARRIER();
    MFMA_Q(0, 0, bF0);
    BARRIER();
    LD_B(bF1, bc, 1);
    STG_HALF(1, Bg, ob, 1, nk - 1);
    VMW(6);
    BARRIER();
    MFMA_Q(0, 1, bF1);
    BARRIER();
    LD_A(bc, 1);
    STG_HALF(0, Ag, ob, 1, nk - 1);
    BARRIER();
    MFMA_Q(1, 1, bF1);
    BARRIER();
    VMW(4);  // retires A0(nk-1), B0(nk-1)
    BARRIER();
    MFMA_Q(1, 0, bF0);
    BARRIER();
  }
  {  // tile nk-1: drain 2 -> 0
    const int bc = (nk - 1) & 1;
    LD_A(bc, 0);
    LD_B(bF0, bc, 0);
    VMW(2);
    BARRIER();
    MFMA_Q(0, 0, bF0);
    BARRIER();
    LD_B(bF1, bc, 1);
    VMW(0);
    BARRIER();
    MFMA_Q(0, 1, bF1);
    BARRIER();
    LD_A(bc, 1);
    BARRIER();
    MFMA_Q(1, 1, bF1);
    MFMA_Q(1, 0, bF0);
  }

#pragma unroll
  for (int nh = 0; nh < 2; nh++)
#pragma unroll
    for (int nf = 0; nf < 2; nf++) {
      const int col = bn * 256 + nh * 128 + wn * 32 + nf * 16 + l15;
      const float bv = (MODE == 0) ? bias[col] : 0.f;
#pragma unroll
      for (int mh = 0; mh < 2; mh++)
#pragma unroll
        for (int mf = 0; mf < 4; mf++) {
          const int row0 = bm * 256 + mh * 128 + wm * 64 + mf * 16 + quad * 4;
#pragma unroll
          for (int r = 0; r < 4; r++) {
            float v = acc[mh * 4 + mf][nh * 2 + nf][r] + bv;
            if (ACT == 1) {
              const float tt = v * (0.7978845608f + 0.0356774081f * v * v);
              v = 0.5f * v * (1.0f + tanhf(tt));
            }
            if (MODE == 0)
              ((u16*)Cv)[(size_t)(row0 + r) * N + col] = f2us(v);
            else
              atomicAdd((float*)Cv + (size_t)(row0 + r) * N + col, v);
          }
        }
    }
#undef STG_HALF
#undef LD_A
#undef LD_B
#undef MFMA_Q
}

// ---------------------------------------------------------------------------
// RoPE in-place on bf16 qkv (q and k sections, first 32 dims of each head).
// ---------------------------------------------------------------------------
__global__ void rope_kernel(u16* __restrict__ qkv, const int* __restrict__ pos) {
  const int idx = blockIdx.x * 256 + threadIdx.x;
  const int i = idx & 15;
  const int which = (idx >> 4) & 1;
  const int hh = (idx >> 5) & 31;
  const int s = idx >> 10;
  const float p = (float)pos[s];
  const float freq = p * expf(-0.57564627324851f * (float)i);
  float sn, c;
  sincosf(freq, &sn, &c);
  u16* base = qkv + (size_t)s * (3 * DMODEL) + which * DMODEL + hh * HDIM + i;
  const float t0 = us2f(base[0]), t1 = us2f(base[16]);
  base[0] = f2us(t0 * c - t1 * sn);
  base[16] = f2us(t1 * c + t0 * sn);
}

// ---------------------------------------------------------------------------
// Flash attention (causal), bf16. Grid (S/64, H), 256 thr = 4 waves; each
// wave owns 16 q-rows. KT=64 keys/iter. hd 80 padded to 96 for 3 K=32 MFMA
// steps. Conflict-free strides: Qs/Ks 104, Vts 88, Ps two 16x40 tiles.
// ---------------------------------------------------------------------------
__global__ void attn_kernel(const u16* __restrict__ qkv, u16* __restrict__ y) {
  const int qt = (int)gridDim.x - 1 - (int)blockIdx.x;  // longest first
  const int h = blockIdx.y;
  const int tid = threadIdx.x, wave = tid >> 6, lane = tid & 63;
  const int quad = lane >> 4, l15 = lane & 15;
  const int qbase = qt * 64;

  __shared__ __align__(16) u16 Qs[64 * 104];
  __shared__ __align__(16) u16 Ks[64 * 104];
  __shared__ __align__(16) u16 Vts[80 * 88];   // [dim][key], stride 88
  __shared__ __align__(16) u16 Ps[4][2][16 * 40];

  for (int i = tid; i < 64 * 104; i += 256) { Qs[i] = 0; Ks[i] = 0; }
  __syncthreads();

  {  // stage Q once, folding in 1/sqrt(80)
    const int r = tid >> 2, c = tid & 3;
    const u16* src = qkv + (size_t)(qbase + r) * (3 * DMODEL) + h * HDIM + c * 20;
    u16* dst = Qs + r * 104 + c * 20;
#pragma unroll
    for (int j = 0; j < 5; j++) {
      ushort4 uv = *(const ushort4*)(src + j * 4);
      ushort4 ov;
      ov.x = f2us(us2f(uv.x) * 0.11180339887f);
      ov.y = f2us(us2f(uv.y) * 0.11180339887f);
      ov.z = f2us(us2f(uv.z) * 0.11180339887f);
      ov.w = f2us(us2f(uv.w) * 0.11180339887f);
      *(ushort4*)(dst + j * 4) = ov;
    }
  }

  float m_i[4], l_i[4];
  f32x4 oacc[5] = {};
#pragma unroll
  for (int r = 0; r < 4; r++) { m_i[r] = -1e30f; l_i[r] = 0.f; }

  const int n_iter = qt + 1;
  __syncthreads();

  for (int it = 0; it < n_iter; ++it) {
    const int kc0 = it * 64;
    if (tid < 128) {  // waves 0-1: stage 64 K rows (2 threads/row)
      const int r = tid >> 1, c = (tid & 1) * 40;
      const u16* src =
          qkv + (size_t)(kc0 + r) * (3 * DMODEL) + DMODEL + h * HDIM + c;
      u16* dst = Ks + r * 104 + c;
#pragma unroll
      for (int j = 0; j < 10; j++)
        *(ushort4*)(dst + j * 4) = *(const ushort4*)(src + j * 4);
    } else {  // waves 2-3: stage 64 V rows transposed
      const int u = tid - 128;
      const int r = u >> 1, c0 = (u & 1) * 40;
      const u16* src =
          qkv + (size_t)(kc0 + r) * (3 * DMODEL) + 2 * DMODEL + h * HDIM + c0;
#pragma unroll
      for (int j = 0; j < 10; j++) {
        ushort4 vv = *(const ushort4*)(src + j * 4);
        const int d0 = c0 + j * 4;
        Vts[(d0 + 0) * 88 + r] = vv.x;
        Vts[(d0 + 1) * 88 + r] = vv.y;
        Vts[(d0 + 2) * 88 + r] = vv.z;
        Vts[(d0 + 3) * 88 + r] = vv.w;
      }
    }
    __syncthreads();

    // S = Q K^T : 16 rows x 64 cols per wave, 3 K-steps over padded hd=96
    f32x4 st[4] = {};
    bf16x8 aq[3];
#pragma unroll
    for (int ks = 0; ks < 3; ks++)
      aq[ks] = *(const bf16x8*)&Qs[(wave * 16 + l15) * 104 + ks * 32 + quad * 8];
#pragma unroll
    for (int ks = 0; ks < 3; ks++)
#pragma unroll
      for (int t = 0; t < 4; t++) {
        bf16x8 bk = *(const bf16x8*)&Ks[(t * 16 + l15) * 104 + ks * 32 + quad * 8];
        st[t] = __builtin_amdgcn_mfma_f32_16x16x32_bf16(aq[ks], bk, st[t], 0, 0, 0);
      }

    // causal mask + online softmax (rows = quad*4+r, cols = t*16+l15)
    float sv[4][4], mx[4];
#pragma unroll
    for (int r = 0; r < 4; r++) {
      const int qr = qbase + wave * 16 + quad * 4 + r;
#pragma unroll
      for (int t = 0; t < 4; t++) {
        const int kc = kc0 + t * 16 + l15;
        sv[t][r] = (kc <= qr) ? st[t][r] : -1e30f;
      }
      mx[r] = fmaxf(fmaxf(sv[0][r], sv[1][r]), fmaxf(sv[2][r], sv[3][r]));
    }
#pragma unroll
    for (int o = 1; o < 16; o <<= 1)
#pragma unroll
      for (int r = 0; r < 4; r++) mx[r] = fmaxf(mx[r], __shfl_xor(mx[r], o, 64));

    float alpha[4], rs[4];
#pragma unroll
    for (int r = 0; r < 4; r++) {
      const float mnew = fmaxf(m_i[r], mx[r]);
      alpha[r] = __expf(m_i[r] - mnew);
      m_i[r] = mnew;
      const float p0 = __expf(sv[0][r] - mnew);
      const float p1 = __expf(sv[1][r] - mnew);
      const float p2 = __expf(sv[2][r] - mnew);
      const float p3 = __expf(sv[3][r] - mnew);
      rs[r] = (p0 + p1) + (p2 + p3);
      const int ro = (quad * 4 + r) * 40;
      Ps[wave][0][ro + l15] = f2us(p0);
      Ps[wave][0][ro + 16 + l15] = f2us(p1);
      Ps[wave][1][ro + l15] = f2us(p2);
      Ps[wave][1][ro + 16 + l15] = f2us(p3);
    }
#pragma unroll
    for (int o = 1; o < 16; o <<= 1)
#pragma unroll
      for (int r = 0; r < 4; r++) rs[r] += __shfl_xor(rs[r], o, 64);
#pragma unroll
    for (int r = 0; r < 4; r++) l_i[r] = l_i[r] * alpha[r] + rs[r];
#pragma unroll
    for (int dt = 0; dt < 5; dt++)
#pragma unroll
      for (int r = 0; r < 4; r++) oacc[dt][r] *= alpha[r];

    // O += P V  (P via per-wave LDS round-trip into A-layout)
    bf16x8 pf0 = *(const bf16x8*)&Ps[wave][0][l15 * 40 + quad * 8];
    bf16x8 pf1 = *(const bf16x8*)&Ps[wave][1][l15 * 40 + quad * 8];
#pragma unroll
    for (int dt = 0; dt < 5; dt++) {
      bf16x8 vf0 = *(const bf16x8*)&Vts[(dt * 16 + l15) * 88 + quad * 8];
      bf16x8 vf1 = *(const bf16x8*)&Vts[(dt * 16 + l15) * 88 + 32 + quad * 8];
      oacc[dt] = __builtin_amdgcn_mfma_f32_16x16x32_bf16(pf0, vf0, oacc[dt], 0, 0, 0);
      oacc[dt] = __builtin_amdgcn_mfma_f32_16x16x32_bf16(pf1, vf1, oacc[dt], 0, 0, 0);
    }
    __syncthreads();
  }

#pragma unroll
  for (int dt = 0; dt < 5; dt++)
#pragma unroll
    for (int r = 0; r < 4; r++) {
      const int row = qbase + wave * 16 + quad * 4 + r;
      y[(size_t)row * DMODEL + h * HDIM + dt * 16 + l15] = f2us(oacc[dt][r] / l_i[r]);
    }
}

extern "C" void kernel_launch(void* const* d_in, const int* in_sizes, int n_in,
                              void* d_out, int out_size, void* d_ws, size_t ws_size,
                              hipStream_t stream) {
  const float* x = (const float*)d_in[0];
  const int* pos = (const int*)d_in[1];
  const float* ln_w = (const float*)d_in[3];
  const float* ln_b = (const float*)d_in[4];
  const float* wqkv_w = (const float*)d_in[5];
  const float* wqkv_b = (const float*)d_in[6];
  const float* wo_w = (const float*)d_in[7];
  const float* wo_b = (const float*)d_in[8];
  const float* w1_w = (const float*)d_in[9];
  const float* w1_b = (const float*)d_in[10];
  const float* w2_w = (const float*)d_in[11];
  const float* w2_b = (const float*)d_in[12];
  float* out = (float*)d_out;

  char* ws = (char*)d_ws;
  // layout (100 MB):
  //   [0,        52428800)  wbuf (bf16 weights, reused 4x)
  //   [52428800, 62914560)  h bf16
  //   [62914560, 104857600) ffn1 bf16 (42MB) -> later qkv (31.5) + yAtt (10.5)
  u16* wbuf = (u16*)(ws);
  u16* h = (u16*)(ws + 52428800);
  u16* ffn1 = (u16*)(ws + 62914560);
  u16* qkv = (u16*)(ws + 62914560);
  u16* yAtt = (u16*)(ws + 94371840);

  ln_kernel<<<S_LEN, 256, 0, stream>>>(x, ln_w, ln_b, h);
  initout_kernel<<<(S_LEN * DMODEL / 4) / 256, 256, 0, stream>>>(x, wo_b, w2_b, out);

  // FFN branch (ffn1 dies before qkv overlays it)
  f2b_kernel<<<(DINTER * DMODEL) / 2048, 256, 0, stream>>>(w1_w, wbuf);
  gemm256<1, 0><<<dim3(DINTER / 256, S_LEN / 256, 1), 512, 0, stream>>>(
      h, wbuf, w1_b, ffn1, S_LEN, DINTER, DMODEL);
  f2b_kernel<<<(DMODEL * DINTER) / 2048, 256, 0, stream>>>(w2_w, wbuf);
  gemm256<0, 2><<<dim3(DMODEL / 256, S_LEN / 256, 5), 512, 0, stream>>>(
      ffn1, wbuf, w2_b, out, S_LEN, DMODEL, DINTER);

  // Attention branch
  f2b_kernel<<<(3 * DMODEL * DMODEL) / 2048, 256, 0, stream>>>(wqkv_w, wbuf);
  gemm256<0, 0><<<dim3(3 * DMODEL / 256, S_LEN / 256, 1), 512, 0, stream>>>(
      h, wbuf, wqkv_b, qkv, S_LEN, 3 * DMODEL, DMODEL);
  rope_kernel<<<(S_LEN * NHEADS * 2 * 16) / 256, 256, 0, stream>>>(qkv, pos);
  attn_kernel<<<dim3(S_LEN / 64, NHEADS), 256, 0, stream>>>(qkv, yAtt);
  f2b_kernel<<<(DMODEL * DMODEL) / 2048, 256, 0, stream>>>(wo_w, wbuf);
  gemm256<0, 2><<<dim3(DMODEL / 256, S_LEN / 256, 2), 512, 0, stream>>>(
      yAtt, wbuf, wo_b, out, S_LEN, DMODEL, DMODEL);
}